// Round 12
// baseline (148.833 us; speedup 1.0000x reference)
//
#include <hip/hip_runtime.h>
#include <hip/hip_bf16.h>
#include <stdint.h>

// Problem constants (B=16, C=256, NH=4, D=64, G=32, L=HW=1024)
// Round 28. R27 counters (attn_proj 54us, VALU 22%, Mfma 14%, HBM 11%,
// FETCH 29MB): latency-bound - qkv is HBM-cold (gemm's x-streaming evicts
// it), occupancy grid-capped at 4 waves/SIMD, and 1-ahead prefetch covers
// only ~1 step (~400cy) vs ~900cy HBM miss. This round:
//  - Prefetch distance 2 for BOTH K and V: 3-set modulo schedule
//    (set = i%3, fully-unrolled loop -> static reg indexing). Load for
//    step i+2 issued at top of step i into the set freed after step i-1
//    -> 2 compute-steps (~800-1000cy) of cover. VGPR ~80->~190 (harmless:
//    grid-capped 4 waves/SIMD, 512 VGPR budget).
//  - proj tail: residual-x float2 loads hoisted above the 16 proj MFMAs.
// All math/layouts identical to R27 (green, absmax 0.03125).

typedef __hip_bfloat16 bf16;
typedef __attribute__((ext_vector_type(8))) short short8;
typedef __attribute__((ext_vector_type(4))) float float4v;
typedef __attribute__((ext_vector_type(16))) float float16v;

#if __has_builtin(__builtin_amdgcn_exp2f)
#define EXP2F(x) __builtin_amdgcn_exp2f(x)
#else
#define EXP2F(x) exp2f(x)
#endif

__device__ __forceinline__ float max3f(float a, float b, float c) {
  return fmaxf(fmaxf(a, b), c);
}
__device__ __forceinline__ unsigned int cvtpk(float lo, float hi) {
  unsigned int pk;
  asm("v_cvt_pk_bf16_f32 %0, %1, %2" : "=v"(pk) : "v"(lo), "v"(hi));
  return pk;
}

// fragment-major index for Q^T/K^T per head: element (d, l) of Q[d][l]
__device__ __forceinline__ int qk_fidx(int d, int l) {
  return ((((l >> 5) * 4 + (d >> 4)) * 64 + ((d >> 3) & 1) * 32 + (l & 31)) << 3) + (d & 7);
}
// fragment-major index for V per head: element (d, l) of V[d][l]
__device__ __forceinline__ int v_fidx(int d, int l) {
  return (((((((l >> 5) * 2 + (d >> 5)) * 2 + ((l >> 4) & 1)) * 2 + ((l >> 3) & 1)) * 32) + (d & 31)) << 3) + (l & 7);
}

// stats (512 blocks) + weight pack (1024 blocks) in one launch.
__global__ __launch_bounds__(256) void stats_wpack_kernel(
    const float* __restrict__ x, float2* __restrict__ stats,
    const float* __restrict__ wq, const float* __restrict__ wk,
    const float* __restrict__ wv, const float* __restrict__ wp,
    bf16* __restrict__ Wb, bf16* __restrict__ Pb) {
  if (blockIdx.x < 512) {
    int b = blockIdx.x >> 5, g = blockIdx.x & 31;
    const float4* xp4 = (const float4*)(x + (size_t)(b * 256 + g * 8) * 1024);
    float s = 0.f, ss = 0.f;
    for (int i = threadIdx.x; i < 2048; i += 256) {
      float4 v = xp4[i];
      s  += (v.x + v.y) + (v.z + v.w);
      ss += (v.x * v.x + v.y * v.y) + (v.z * v.z + v.w * v.w);
    }
    #pragma unroll
    for (int o = 32; o; o >>= 1) { s += __shfl_down(s, o); ss += __shfl_down(ss, o); }
    __shared__ float red[2][4];
    int wid = threadIdx.x >> 6;
    if ((threadIdx.x & 63) == 0) { red[0][wid] = s; red[1][wid] = ss; }
    __syncthreads();
    if (threadIdx.x == 0) {
      s  = red[0][0] + red[0][1] + red[0][2] + red[0][3];
      ss = red[1][0] + red[1][1] + red[1][2] + red[1][3];
      float mean = s * (1.f / 8192.f);
      float var  = ss * (1.f / 8192.f) - mean * mean;
      stats[blockIdx.x] = make_float2(mean, rsqrtf(var + 1e-5f));
    }
  } else {
    int i = (blockIdx.x - 512) * 256 + threadIdx.x;   // 262144 total
    if (i < 196608) {
      int r = i >> 8, c = i & 255;
      const float* src = (r < 256) ? wq : (r < 512) ? wk : wv;
      Wb[i] = __float2bfloat16(src[(r & 255) * 256 + c]);
    } else {
      int j2 = i - 196608;                            // 0..65535
      int jj = j2 & 7, lane2 = (j2 >> 3) & 63;
      int kk2 = (j2 >> 9) & 15, w2 = j2 >> 13;
      int m = w2 * 32 + (lane2 & 31);
      int e = kk2 * 16 + (lane2 >> 5) * 8 + jj;
      Pb[j2] = __float2bfloat16(wp[m * 256 + e]);
    }
  }
}

// Fused GN + qkv GEMM (unchanged from R27).
__global__ __launch_bounds__(256) void gemm_qkv_fused(
    const float* __restrict__ x, const float* __restrict__ gamma,
    const float* __restrict__ beta, const float2* __restrict__ stats,
    const bf16* __restrict__ Wb,
    const float* __restrict__ bq, const float* __restrict__ bk,
    const float* __restrict__ bv,
    bf16* __restrict__ qkv, size_t qkv_bstride, int b_off) {
  __shared__ bf16 As[128][40];
  __shared__ bf16 Bs[128][40];
  __shared__ float2 ssh[256];
  int zb, m0, l0;
  if (gridDim.x == 768) {
    int f = blockIdx.x;
    int c = f & 7, t = f >> 3;
    zb = (t & 1) * 8 + c;                 // wgid%8 == zb%8 -> XCD match
    int rem = t >> 1;                     // 0..47
    m0 = (rem % 6) * 128;
    l0 = (rem / 6) * 128;
  } else {
    zb = blockIdx.z; m0 = blockIdx.y * 128; l0 = blockIdx.x * 128;
  }
  int b = zb + b_off;
  const float* xb = x + (size_t)b * 262144;
  int tid = threadIdx.x, lane = tid & 63, wave = tid >> 6;
  int l16 = lane & 15, quad = lane >> 4;
  int mi0 = (wave & 1) * 4, nj0 = (wave >> 1) * 4;

  {
    float2 st = stats[b * 32 + (tid >> 3)];
    float sc = st.y * gamma[tid];
    ssh[tid] = make_float2(sc, beta[tid] - st.x * sc);
  }

  float4v acc[4][4];
  #pragma unroll
  for (int i = 0; i < 4; i++)
    #pragma unroll
    for (int j = 0; j < 4; j++) acc[i][j] = (float4v){0.f, 0.f, 0.f, 0.f};

  for (int kc = 0; kc < 8; kc++) {
    __syncthreads();
    #pragma unroll
    for (int it = 0; it < 2; it++) {
      int s = it * 256 + tid;
      int mm = s >> 2, kk = (s & 3) * 8;
      *(short8*)&As[mm][kk] = *(const short8*)&Wb[(size_t)(m0 + mm) * 256 + kc * 32 + kk];
    }
    // B tile: 32 c x 128 l; thread -> (ll, cg*4..cg*4+3)
    #pragma unroll
    for (int it = 0; it < 4; it++) {
      int s = it * 256 + tid;
      int ll = s & 127, cg = s >> 7;               // cg 0..7
      int c = kc * 32 + cg * 4;
      float2 sh0 = ssh[c], sh1 = ssh[c + 1], sh2 = ssh[c + 2], sh3 = ssh[c + 3];
      const float* xp = &xb[(size_t)c * 1024 + l0 + ll];
      float v0 = xp[0]    * sh0.x + sh0.y;
      float v1 = xp[1024] * sh1.x + sh1.y;
      float v2 = xp[2048] * sh2.x + sh2.y;
      float v3 = xp[3072] * sh3.x + sh3.y;
      uint2 pk;
      pk.x = cvtpk(v0, v1);
      pk.y = cvtpk(v2, v3);
      *(uint2*)&Bs[ll][cg * 4] = pk;
    }
    __syncthreads();
    short8 af[4], bfr[4];
    #pragma unroll
    for (int i = 0; i < 4; i++) af[i]  = *(const short8*)&As[(mi0 + i) * 16 + l16][quad * 8];
    #pragma unroll
    for (int j = 0; j < 4; j++) bfr[j] = *(const short8*)&Bs[(nj0 + j) * 16 + l16][quad * 8];
    #pragma unroll
    for (int i = 0; i < 4; i++)
      #pragma unroll
      for (int j = 0; j < 4; j++)
        acc[i][j] = __builtin_amdgcn_mfma_f32_16x16x32_bf16(af[i], bfr[j], acc[i][j], 0, 0, 0);
  }

  bf16* Cp = qkv + (size_t)zb * qkv_bstride;
  int sec = m0 >> 8;
  const float* bptr = (sec == 0) ? bq : (sec == 1) ? bk : bv;
  if (sec <= 1) {
    float osc = (sec == 0) ? 0.125f * 1.4426950408889634f : 1.0f;
    bf16* Tp = Cp + sec * 262144;
    #pragma unroll
    for (int i = 0; i < 4; i++) {
      int rrb = (m0 & 255) + (mi0 + i) * 16 + quad * 4;
      int nh = rrb >> 6, d0 = rrb & 63;
      float b0 = bptr[rrb], b1 = bptr[rrb + 1], b2 = bptr[rrb + 2], b3 = bptr[rrb + 3];
      bf16* Tph = Tp + nh * 65536;
      #pragma unroll
      for (int j = 0; j < 4; j++) {
        int l = l0 + (nj0 + j) * 16 + l16;
        uint2 pk;
        pk.x = cvtpk((acc[i][j][0] + b0) * osc, (acc[i][j][1] + b1) * osc);
        pk.y = cvtpk((acc[i][j][2] + b2) * osc, (acc[i][j][3] + b3) * osc);
        *(uint2*)&Tph[qk_fidx(d0, l)] = pk;
      }
    }
  } else {
    bf16* Vfp = Cp + 524288;
    #pragma unroll
    for (int i = 0; i < 4; i++)
      #pragma unroll
      for (int rp = 0; rp < 2; rp++) {
        int rr = (m0 & 255) + (mi0 + i) * 16 + quad * 4 + rp * 2;
        int nh = rr >> 6, d = rr & 63;
        float b0 = bptr[rr], b1 = bptr[rr + 1];
        bf16* Vfh = Vfp + nh * 65536;
        #pragma unroll
        for (int j = 0; j < 4; j++) {
          int l = l0 + (nj0 + j) * 16 + l16;
          unsigned int pk = cvtpk(acc[i][j][rp * 2] + b0, acc[i][j][rp * 2 + 1] + b1);
          *(unsigned short*)&Vfh[v_fidx(d, l)] = (unsigned short)pk;
          *(unsigned short*)&Vfh[v_fidx(d + 1, l)] = (unsigned short)(pk >> 16);
        }
      }
  }
}

// Fused flash attention + output projection + residual.
// kt loop: prefetch distance 2 for K AND V via 3-set modulo schedule
// (fully unrolled -> static register indexing).
__global__ __launch_bounds__(512) void attn_proj_kernel(
    const bf16* __restrict__ qkv, const bf16* __restrict__ PbF,
    const float* __restrict__ bproj, const float* __restrict__ x,
    float* __restrict__ out, size_t qkv_bstride, int b_off) {
  __shared__ __align__(16) char lds[52736];
  float* OB   = (float*)lds;              // [4 heads][32 q][68] f32 = 34816 B
  float* mL   = (float*)(lds + 34816);    // [4][32]
  float* lL   = (float*)(lds + 35328);    // [4][32]
  bf16*  O_lds = (bf16*)(lds + 35840);    // [32 q][264 e] = 16896 B

  int b, qg;
  {
    int f = blockIdx.x;
    if (gridDim.x == 512) {               // XCD swizzle: wgid%8 == b%8
      int c = f & 7, t = f >> 3;
      b = ((t & 1) << 3) + c; qg = t >> 1;
    } else {
      b = b_off; qg = f;
    }
  }
  const bf16* base = qkv + (size_t)(gridDim.x == 512 ? b : 0) * qkv_bstride;
  int tid = threadIdx.x;
  int lane = tid & 63, wave = tid >> 6;
  int l31 = lane & 31, hb2 = lane >> 5;
  int n = wave & 3, half = wave >> 2;
  const bf16* Qf = base + n * 65536;
  const bf16* Kf = base + 262144 + n * 65536;
  const bf16* Vf = base + 524288 + n * 65536;

  short8 qb[4];
  #pragma unroll
  for (int ds = 0; ds < 4; ds++)
    qb[ds] = *(const short8*)&Qf[(((qg * 4 + ds) << 6) + lane) << 3];

  float m_run = -1e30f, l_run = 0.f;
  float16v oaccT[2];
  #pragma unroll
  for (int dh = 0; dh < 2; dh++)
    #pragma unroll
    for (int r = 0; r < 16; r++) oaccT[dh][r] = 0.f;

  auto swp = [&](unsigned int a, unsigned int bb, unsigned int& o0, unsigned int& o1) {
#if __has_builtin(__builtin_amdgcn_permlane32_swap)
    auto rr = __builtin_amdgcn_permlane32_swap((int)a, (int)bb, false, false);
    o0 = (unsigned int)rr[0]; o1 = (unsigned int)rr[1];
#else
    unsigned int sa = (unsigned int)__shfl_xor((int)a, 32, 64);
    unsigned int sb = (unsigned int)__shfl_xor((int)bb, 32, 64);
    o0 = hb2 ? sb : a;
    o1 = hb2 ? bb : sa;
#endif
  };

  // 3-set K/V prefetch buffers
  short8 kS[3][4], vS[3][2][2];

  auto loadKV = [&](int set, int kt) {
    #pragma unroll
    for (int ds = 0; ds < 4; ds++)
      kS[set][ds] = *(const short8*)&Kf[(((kt * 4 + ds) << 6) + lane) << 3];
    #pragma unroll
    for (int dh = 0; dh < 2; dh++)
      #pragma unroll
      for (int s = 0; s < 2; s++)
        vS[set][dh][s] = *(const short8*)&Vf[((((kt * 2 + dh) * 2 + s) << 6) + lane) << 3];
  };

  auto step = [&](int set) {
    float16v sacc;
    #pragma unroll
    for (int r = 0; r < 16; r++) sacc[r] = 0.f;
    #pragma unroll
    for (int ds = 0; ds < 4; ds++)
      sacc = __builtin_amdgcn_mfma_f32_32x32x16_bf16(kS[set][ds], qb[ds], sacc, 0, 0, 0);

    float a0 = max3f(sacc[0], sacc[1], sacc[2]);
    float a1 = max3f(sacc[3], sacc[4], sacc[5]);
    float a2 = max3f(sacc[6], sacc[7], sacc[8]);
    float a3 = max3f(sacc[9], sacc[10], sacc[11]);
    float a4 = max3f(sacc[12], sacc[13], sacc[14]);
    float cmax = fmaxf(max3f(a0, a1, a2), max3f(a3, a4, sacc[15]));
    cmax = fmaxf(cmax, __shfl_xor(cmax, 32, 64));

    if (__any(cmax > m_run + 8.f)) {
      float mnew = fmaxf(m_run, cmax);
      float alpha = EXP2F(m_run - mnew);
      #pragma unroll
      for (int dh = 0; dh < 2; dh++)
        #pragma unroll
        for (int r = 0; r < 16; r++) oaccT[dh][r] *= alpha;
      l_run *= alpha;
      m_run = mnew;
    }

    float p[16];
    #pragma unroll
    for (int r = 0; r < 16; r++) p[r] = EXP2F(sacc[r] - m_run);
    float s0 = (p[0] + p[1]) + (p[2] + p[3]);
    float s1 = (p[4] + p[5]) + (p[6] + p[7]);
    float s2 = (p[8] + p[9]) + (p[10] + p[11]);
    float s3 = (p[12] + p[13]) + (p[14] + p[15]);
    float psum = (s0 + s1) + (s2 + s3);
    psum += __shfl_xor(psum, 32, 64);
    l_run += psum;

    unsigned int w[8];
    #pragma unroll
    for (int i = 0; i < 8; i++) w[i] = cvtpk(p[2 * i], p[2 * i + 1]);
    short8 pb[2];
    {
      unsigned int o0, o1, o2, o3;
      swp(w[0], w[2], o0, o2); swp(w[1], w[3], o1, o3);
      unsigned int* pw = (unsigned int*)&pb[0];
      pw[0] = o0; pw[1] = o1; pw[2] = o2; pw[3] = o3;
      swp(w[4], w[6], o0, o2); swp(w[5], w[7], o1, o3);
      pw = (unsigned int*)&pb[1];
      pw[0] = o0; pw[1] = o1; pw[2] = o2; pw[3] = o3;
    }

    #pragma unroll
    for (int dh = 0; dh < 2; dh++)
      #pragma unroll
      for (int s = 0; s < 2; s++)
        oaccT[dh] = __builtin_amdgcn_mfma_f32_32x32x16_bf16(vS[set][dh][s], pb[s], oaccT[dh], 0, 0, 0);
  };

  // kt loop: distance-2 modulo schedule over 3 sets (fully unrolled)
  int k0 = half << 4;
  loadKV(0, k0);
  loadKV(1, k0 + 1);
  #pragma unroll
  for (int i = 0; i < 16; i++) {
    if (i + 2 < 16) loadKV((i + 2) % 3, k0 + i + 2);
    step(i % 3);
  }

  // half-1 waves dump partials; half-0 waves merge -> O_lds (bf16)
  if (half == 1) {
    float* OBn = OB + n * 2176;
    #pragma unroll
    for (int dh = 0; dh < 2; dh++)
      #pragma unroll
      for (int rq = 0; rq < 4; rq++) {
        float4v t = {oaccT[dh][4 * rq], oaccT[dh][4 * rq + 1],
                     oaccT[dh][4 * rq + 2], oaccT[dh][4 * rq + 3]};
        *(float4v*)&OBn[l31 * 68 + dh * 32 + 8 * rq + 4 * hb2] = t;
      }
    if (hb2 == 0) { mL[n * 32 + l31] = m_run; lL[n * 32 + l31] = l_run; }
  }
  __syncthreads();
  if (half == 0) {
    float mB = mL[n * 32 + l31], lB = lL[n * 32 + l31];
    float ms = fmaxf(m_run, mB);
    float eA = EXP2F(m_run - ms), eB = EXP2F(mB - ms);
    float inv = 1.f / (l_run * eA + lB * eB);
    eA *= inv; eB *= inv;
    const float* OBn = OB + n * 2176 + l31 * 68;
    bf16* orow = O_lds + l31 * 264 + n * 64;
    #pragma unroll
    for (int dh = 0; dh < 2; dh++)
      #pragma unroll
      for (int rp = 0; rp < 8; rp++) {
        int r = rp * 2;
        int d = dh * 32 + (r & 3) + 8 * (r >> 2) + 4 * hb2;
        unsigned int pk = cvtpk(oaccT[dh][r] * eA + OBn[d] * eB,
                                oaccT[dh][r + 1] * eA + OBn[d + 1] * eB);
        *(unsigned int*)&orow[d] = pk;
      }
  }
  __syncthreads();

  // proj: wave w -> out rows m = 32w .. 32w+31 for l = qg*32 .. +31
  int m = (wave << 5) + l31;
  float bias = bproj[m];
  const float* xr = x + (((size_t)(b * 256 + m)) << 10) + (qg << 5);
  float* orw = out + (((size_t)(b * 256 + m)) << 10) + (qg << 5);
  // hoist residual loads above the MFMA chain (HBM latency cover)
  float2 xv[8];
  #pragma unroll
  for (int rp = 0; rp < 8; rp++) {
    int ll = ((rp * 2) & 3) + 8 * ((rp * 2) >> 2) + 4 * hb2;
    xv[rp] = *(const float2*)&xr[ll];
  }
  float16v pacc;
  #pragma unroll
  for (int r = 0; r < 16; r++) pacc[r] = 0.f;
  #pragma unroll
  for (int kk = 0; kk < 16; kk++) {
    short8 a = *(const short8*)&O_lds[l31 * 264 + kk * 16 + hb2 * 8];
    short8 bb = *(const short8*)&PbF[(((wave * 16 + kk) << 6) + lane) << 3];
    pacc = __builtin_amdgcn_mfma_f32_32x32x16_bf16(a, bb, pacc, 0, 0, 0);
  }
  #pragma unroll
  for (int rp = 0; rp < 8; rp++) {
    int r = rp * 2;
    int ll = (r & 3) + 8 * (r >> 2) + 4 * hb2;
    float2 ov;
    ov.x = pacc[r] + bias + xv[rp].x;
    ov.y = pacc[r + 1] + bias + xv[rp].y;
    *(float2*)&orw[ll] = ov;
  }
}

extern "C" void kernel_launch(void* const* d_in, const int* in_sizes, int n_in,
                              void* d_out, int out_size, void* d_ws, size_t ws_size,
                              hipStream_t stream) {
  int ix = 0, iga = 1, ibe = 2, iwq = 3, ibq = 4, iwk = 5, ibk = 6,
      iwv = 7, ibv = 8, iwp = 9, ibp = 10;
  if (in_sizes[0] != 4194304) {
    if (in_sizes[10] == 4194304 && in_sizes[1] == 256) {
      ibe = 0; ibk = 1; ibp = 2; ibq = 3; ibv = 4; iga = 5;
      iwk = 6; iwp = 7; iwq = 8; iwv = 9; ix = 10;
    } else if (in_sizes[10] == 4194304 && in_sizes[1] == 65536) {
      ibp = 0; iwp = 1; ibv = 2; iwv = 3; ibk = 4; iwk = 5;
      ibq = 6; iwq = 7; ibe = 8; iga = 9; ix = 10;
    } else {
      for (int i = 0; i < 11; i++) if (in_sizes[i] == 4194304) ix = i;
    }
  }
  const float* x     = (const float*)d_in[ix];
  const float* gamma = (const float*)d_in[iga];
  const float* beta  = (const float*)d_in[ibe];
  const float* wq    = (const float*)d_in[iwq];
  const float* bq    = (const float*)d_in[ibq];
  const float* wk    = (const float*)d_in[iwk];
  const float* bk    = (const float*)d_in[ibk];
  const float* wv    = (const float*)d_in[iwv];
  const float* bv    = (const float*)d_in[ibv];
  const float* wproj = (const float*)d_in[iwp];
  const float* bproj = (const float*)d_in[ibp];
  float* out = (float*)d_out;

  const size_t QKV_B = (size_t)768 * 1024;   // elements per batch
  char* wsp = (char*)d_ws;
  float2* stats = (float2*)wsp;                        // 4 KB
  bf16* Wb = (bf16*)(wsp + 8192);                      // 384 KB
  bf16* Pb = (bf16*)(wsp + 8192 + 393216);             // 128 KB (frag-major)
  const size_t QKV0 = 8192 + 393216 + 131072;
  size_t full_need = QKV0 + (size_t)16 * QKV_B * 2;    // ~24.7 MB

  stats_wpack_kernel<<<1536, 256, 0, stream>>>(x, stats, wq, wk, wv, wproj, Wb, Pb);

  if (ws_size >= full_need) {
    bf16* qkv = (bf16*)(wsp + QKV0);                   // 24 MB
    gemm_qkv_fused<<<768, 256, 0, stream>>>(x, gamma, beta, stats, Wb,
                                            bq, bk, bv, qkv, QKV_B, 0);
    attn_proj_kernel<<<512, 512, 0, stream>>>(qkv, Pb, bproj, x, out, QKV_B, 0);
  } else {
    bf16* qkv = (bf16*)(wsp + QKV0);
    for (int b = 0; b < 16; b++) {
      gemm_qkv_fused<<<dim3(8, 6, 1), 256, 0, stream>>>(x, gamma, beta, stats, Wb,
                                                        bq, bk, bv, qkv, 0, b);
      attn_proj_kernel<<<32, 512, 0, stream>>>(qkv, Pb, bproj, x, out, 0, b);
    }
  }
}